// Round 3
// baseline (331.552 us; speedup 1.0000x reference)
//
#include <hip/hip_runtime.h>
#include <hip/hip_cooperative_groups.h>
#include <cstdint>
#include <cstddef>

namespace cg = cooperative_groups;

#define NODES 20000
#define NEDGE 320000
#define CAP 64            // padded CSR capacity per node (max deg ~34 at 16+/-4)
#define NGRP (NODES / 8)  // 2500 gpost groups
#define LINB 16           // lin conversion blocks (16*256 = 4096 elems)
#define BIGB 32           // BigW blocks (32 blocks * 4 rows = 128 rows)

using bf16x8 = __attribute__((ext_vector_type(8))) __bf16;
using f32x4  = __attribute__((ext_vector_type(4))) float;
using f32x2  = __attribute__((ext_vector_type(2))) float;
using i32x4  = __attribute__((ext_vector_type(4))) int;

__device__ __forceinline__ unsigned short f2bf(float f) {
  union { float f; unsigned int u; } v; v.f = f;
  unsigned int r = v.u + 0x7FFF + ((v.u >> 16) & 1);  // RNE
  return (unsigned short)(r >> 16);
}

#define DECACC(u, s0, s1, s2, s3)                               \
  {                                                             \
    f32x2 lo_ = __builtin_amdgcn_cvt_pk_f32_fp8(u, false);      \
    f32x2 hi_ = __builtin_amdgcn_cvt_pk_f32_fp8(u, true);       \
    s0 += lo_.x; s1 += lo_.y; s2 += hi_.x; s3 += hi_.y;         \
  }

// ---- single fused cooperative kernel ----
// P0 zero cnt | sync | P1 edge-scatter + weight prep | sync | P2 xconv
// | sync | P3 gather+lin+sigmoid+BigW+relu (grid-stride over 2500 groups)
__global__ void k_all(const float* __restrict__ x, const int* __restrict__ ei,
                      const float* __restrict__ lin, const float* __restrict__ bias,
                      const float* __restrict__ u1, const float* __restrict__ u2,
                      const float* __restrict__ l1, const float* __restrict__ l2,
                      const float* __restrict__ lastw, float* __restrict__ out,
                      int* __restrict__ cnt, int* __restrict__ csr,
                      unsigned int* __restrict__ xs8, float* __restrict__ dis,
                      unsigned short* __restrict__ wb16) {
  cg::grid_group gg = cg::this_grid();
  __shared__ __attribute__((aligned(16))) char smraw[9216];
  int t = threadIdx.x, bid = blockIdx.x, gsz = gridDim.x;
  int gtid = bid * 256 + t, gthr = gsz * 256;

  // ---------- P0: zero cnt ----------
  for (int i = gtid; i < NODES; i += gthr) cnt[i] = 0;
  gg.sync();

  // ---------- P1: edge scatter (grid-stride) ----------
  for (int i = gtid; i < NEDGE; i += gthr) {
    int r = ei[i], c = ei[NEDGE + i];
    int p = atomicAdd(&cnt[c], 1);
    if (p < CAP) csr[c * CAP + p] = r;
  }
  // ---------- P1b: weight prep (dedicated low blocks) ----------
  if (bid < LINB) {
    int g = bid * 256 + t;  // [0,4096)
    wb16[g] = f2bf(lin[g]);
  } else if (bid < LINB + BIGB) {
    float (*tmp_u)[64] = (float(*)[64])smraw;
    float (*tmp_l)[64] = (float(*)[64])(smraw + 1024);
    int o0 = (bid - LINB) * 4;
    int ol = t >> 6, p = t & 63;
    float su = 0.f, sl = 0.f;
    for (int k = 0; k < 64; ++k) {
      float lu = lastw[(o0 + ol) * 128 + k];
      float ll = lastw[(o0 + ol) * 128 + 64 + k];
      su += lu * u2[k * 64 + p];
      sl += ll * l2[k * 64 + p];
    }
    tmp_u[ol][p] = su;
    tmp_l[ol][p] = sl;
    __syncthreads();
    float acc = 0.f;
    for (int q = 0; q < 64; ++q)
      acc += tmp_u[ol][q] * u1[q * 64 + p] + tmp_l[ol][q] * l1[q * 64 + p];
    wb16[4096 + (o0 + ol) * 64 + p] = f2bf(acc);
  }
  gg.sync();

  // ---------- P2: xconv (grid-stride) ----------
  for (int g = gtid; g < NODES * 64; g += gthr) {
    int n = g >> 6, i = g & 63;
    int b = i >> 4, c = (i & 15) * 4;
    float ds = rsqrtf((float)(cnt[n] + 1));  // +1 = self loop
    if (i == 0) dis[n] = ds;
    f32x4 v = __builtin_nontemporal_load(
        (const f32x4*)(x + ((size_t)b * NODES + n) * 64 + c));
    int pk = 0;
    pk = __builtin_amdgcn_cvt_pk_fp8_f32(v.x * ds, v.y * ds, pk, false);
    pk = __builtin_amdgcn_cvt_pk_fp8_f32(v.z * ds, v.w * ds, pk, true);
    xs8[(size_t)n * 64 + i] = (unsigned int)pk;
  }
  gg.sync();

  // ---------- P3: fused gather + lin + sigmoid + BigW + relu ----------
  unsigned short (*xa)[72]  = (unsigned short(*)[72])smraw;
  unsigned short (*fst)[72] = (unsigned short(*)[72])(smraw + 4608);
  int w = t >> 6, l = t & 63;
  int m = l & 15, q = l >> 4;
  const unsigned short* wlin = wb16;
  const unsigned short* bigw = wb16 + 4096;

  // loop-invariant weight/bias prefetch (wb16 final after sync above)
  bf16x8 wa0  = *(const bf16x8*)(wlin + (16 * w + m) * 64 + q * 8);
  bf16x8 wa1  = *(const bf16x8*)(wlin + (16 * w + m) * 64 + q * 8 + 32);
  bf16x8 wb00 = *(const bf16x8*)(bigw + (32 * w + m) * 64 + q * 8);
  bf16x8 wb10 = *(const bf16x8*)(bigw + (32 * w + 16 + m) * 64 + q * 8);
  bf16x8 wb01 = *(const bf16x8*)(bigw + (32 * w + m) * 64 + q * 8 + 32);
  bf16x8 wb11 = *(const bf16x8*)(bigw + (32 * w + 16 + m) * 64 + q * 8 + 32);
  float4 b4 = *(const float4*)(bias + 16 * w + 4 * q);

  for (int grp = bid; grp < NGRP; grp += gsz) {
    int n0 = grp * 8;
    int nA = n0 + 2 * w;

    int2 cc = *(const int2*)(cnt + nA);
    int dA = cc.x > CAP ? CAP : cc.x;
    int dB = cc.y > CAP ? CAP : cc.y;

    float ds0 = dis[n0 + (m >> 2)];       // nt=0 rows
    float ds1 = dis[n0 + 4 + (m >> 2)];   // nt=1 rows

    float aA0, aA1, aA2, aA3, aB0, aB1, aB2, aB3;
    {
      unsigned int uA = xs8[(size_t)nA * 64 + l];        // self loop A
      unsigned int uB = xs8[(size_t)(nA + 1) * 64 + l];  // self loop B
      f32x2 lo = __builtin_amdgcn_cvt_pk_f32_fp8(uA, false);
      f32x2 hi = __builtin_amdgcn_cvt_pk_f32_fp8(uA, true);
      aA0 = lo.x; aA1 = lo.y; aA2 = hi.x; aA3 = hi.y;
      lo = __builtin_amdgcn_cvt_pk_f32_fp8(uB, false);
      hi = __builtin_amdgcn_cvt_pk_f32_fp8(uB, true);
      aB0 = lo.x; aB1 = lo.y; aB2 = hi.x; aB3 = hi.y;
    }

    int iA = nA * CAP, eA = iA + dA;
    int iB = iA + CAP, eB = iB + dB;

    while (iA + 8 <= eA && iB + 8 <= eB) {
      i32x4 ra0 = __builtin_nontemporal_load((const i32x4*)(csr + iA));
      i32x4 ra1 = __builtin_nontemporal_load((const i32x4*)(csr + iA + 4));
      i32x4 rb0 = __builtin_nontemporal_load((const i32x4*)(csr + iB));
      i32x4 rb1 = __builtin_nontemporal_load((const i32x4*)(csr + iB + 4));
      unsigned int uA0 = xs8[(size_t)ra0.x * 64 + l];
      unsigned int uA1 = xs8[(size_t)ra0.y * 64 + l];
      unsigned int uA2 = xs8[(size_t)ra0.z * 64 + l];
      unsigned int uA3 = xs8[(size_t)ra0.w * 64 + l];
      unsigned int uA4 = xs8[(size_t)ra1.x * 64 + l];
      unsigned int uA5 = xs8[(size_t)ra1.y * 64 + l];
      unsigned int uA6 = xs8[(size_t)ra1.z * 64 + l];
      unsigned int uA7 = xs8[(size_t)ra1.w * 64 + l];
      unsigned int uB0 = xs8[(size_t)rb0.x * 64 + l];
      unsigned int uB1 = xs8[(size_t)rb0.y * 64 + l];
      unsigned int uB2 = xs8[(size_t)rb0.z * 64 + l];
      unsigned int uB3 = xs8[(size_t)rb0.w * 64 + l];
      unsigned int uB4 = xs8[(size_t)rb1.x * 64 + l];
      unsigned int uB5 = xs8[(size_t)rb1.y * 64 + l];
      unsigned int uB6 = xs8[(size_t)rb1.z * 64 + l];
      unsigned int uB7 = xs8[(size_t)rb1.w * 64 + l];
      DECACC(uA0, aA0, aA1, aA2, aA3); DECACC(uA1, aA0, aA1, aA2, aA3);
      DECACC(uA2, aA0, aA1, aA2, aA3); DECACC(uA3, aA0, aA1, aA2, aA3);
      DECACC(uA4, aA0, aA1, aA2, aA3); DECACC(uA5, aA0, aA1, aA2, aA3);
      DECACC(uA6, aA0, aA1, aA2, aA3); DECACC(uA7, aA0, aA1, aA2, aA3);
      DECACC(uB0, aB0, aB1, aB2, aB3); DECACC(uB1, aB0, aB1, aB2, aB3);
      DECACC(uB2, aB0, aB1, aB2, aB3); DECACC(uB3, aB0, aB1, aB2, aB3);
      DECACC(uB4, aB0, aB1, aB2, aB3); DECACC(uB5, aB0, aB1, aB2, aB3);
      DECACC(uB6, aB0, aB1, aB2, aB3); DECACC(uB7, aB0, aB1, aB2, aB3);
      iA += 8; iB += 8;
    }
    while (iA + 8 <= eA) {
      i32x4 r0 = __builtin_nontemporal_load((const i32x4*)(csr + iA));
      i32x4 r1 = __builtin_nontemporal_load((const i32x4*)(csr + iA + 4));
      unsigned int u0 = xs8[(size_t)r0.x * 64 + l];
      unsigned int u1 = xs8[(size_t)r0.y * 64 + l];
      unsigned int u2 = xs8[(size_t)r0.z * 64 + l];
      unsigned int u3 = xs8[(size_t)r0.w * 64 + l];
      unsigned int u4 = xs8[(size_t)r1.x * 64 + l];
      unsigned int u5 = xs8[(size_t)r1.y * 64 + l];
      unsigned int u6 = xs8[(size_t)r1.z * 64 + l];
      unsigned int u7 = xs8[(size_t)r1.w * 64 + l];
      DECACC(u0, aA0, aA1, aA2, aA3); DECACC(u1, aA0, aA1, aA2, aA3);
      DECACC(u2, aA0, aA1, aA2, aA3); DECACC(u3, aA0, aA1, aA2, aA3);
      DECACC(u4, aA0, aA1, aA2, aA3); DECACC(u5, aA0, aA1, aA2, aA3);
      DECACC(u6, aA0, aA1, aA2, aA3); DECACC(u7, aA0, aA1, aA2, aA3);
      iA += 8;
    }
    while (iB + 8 <= eB) {
      i32x4 r0 = __builtin_nontemporal_load((const i32x4*)(csr + iB));
      i32x4 r1 = __builtin_nontemporal_load((const i32x4*)(csr + iB + 4));
      unsigned int u0 = xs8[(size_t)r0.x * 64 + l];
      unsigned int u1 = xs8[(size_t)r0.y * 64 + l];
      unsigned int u2 = xs8[(size_t)r0.z * 64 + l];
      unsigned int u3 = xs8[(size_t)r0.w * 64 + l];
      unsigned int u4 = xs8[(size_t)r1.x * 64 + l];
      unsigned int u5 = xs8[(size_t)r1.y * 64 + l];
      unsigned int u6 = xs8[(size_t)r1.z * 64 + l];
      unsigned int u7 = xs8[(size_t)r1.w * 64 + l];
      DECACC(u0, aB0, aB1, aB2, aB3); DECACC(u1, aB0, aB1, aB2, aB3);
      DECACC(u2, aB0, aB1, aB2, aB3); DECACC(u3, aB0, aB1, aB2, aB3);
      DECACC(u4, aB0, aB1, aB2, aB3); DECACC(u5, aB0, aB1, aB2, aB3);
      DECACC(u6, aB0, aB1, aB2, aB3); DECACC(u7, aB0, aB1, aB2, aB3);
      iB += 8;
    }
    while (iA + 4 <= eA) {
      i32x4 r0 = __builtin_nontemporal_load((const i32x4*)(csr + iA));
      unsigned int u0 = xs8[(size_t)r0.x * 64 + l];
      unsigned int u1 = xs8[(size_t)r0.y * 64 + l];
      unsigned int u2 = xs8[(size_t)r0.z * 64 + l];
      unsigned int u3 = xs8[(size_t)r0.w * 64 + l];
      DECACC(u0, aA0, aA1, aA2, aA3); DECACC(u1, aA0, aA1, aA2, aA3);
      DECACC(u2, aA0, aA1, aA2, aA3); DECACC(u3, aA0, aA1, aA2, aA3);
      iA += 4;
    }
    while (iB + 4 <= eB) {
      i32x4 r0 = __builtin_nontemporal_load((const i32x4*)(csr + iB));
      unsigned int u0 = xs8[(size_t)r0.x * 64 + l];
      unsigned int u1 = xs8[(size_t)r0.y * 64 + l];
      unsigned int u2 = xs8[(size_t)r0.z * 64 + l];
      unsigned int u3 = xs8[(size_t)r0.w * 64 + l];
      DECACC(u0, aB0, aB1, aB2, aB3); DECACC(u1, aB0, aB1, aB2, aB3);
      DECACC(u2, aB0, aB1, aB2, aB3); DECACC(u3, aB0, aB1, aB2, aB3);
      iB += 4;
    }
    for (; iA < eA; ++iA) {
      unsigned int u = xs8[(size_t)csr[iA] * 64 + l];
      DECACC(u, aA0, aA1, aA2, aA3);
    }
    for (; iB < eB; ++iB) {
      unsigned int u = xs8[(size_t)csr[iB] * 64 + l];
      DECACC(u, aB0, aB1, aB2, aB3);
    }

    {
      ushort4 o;
      o.x = f2bf(aA0); o.y = f2bf(aA1); o.z = f2bf(aA2); o.w = f2bf(aA3);
      *(ushort4*)&xa[(2 * w) * 4 + (l >> 4)][(l & 15) * 4] = o;
      o.x = f2bf(aB0); o.y = f2bf(aB1); o.z = f2bf(aB2); o.w = f2bf(aB3);
      *(ushort4*)&xa[(2 * w + 1) * 4 + (l >> 4)][(l & 15) * 4] = o;
    }
    __syncthreads();

    // stage1 (swapped): fst = sigmoid(h*dis+bias)
    {
      f32x4 acc10 = {0, 0, 0, 0}, acc11 = {0, 0, 0, 0};
      bf16x8 x00 = *(const bf16x8*)&xa[m][q * 8];
      bf16x8 x10 = *(const bf16x8*)&xa[16 + m][q * 8];
      acc10 = __builtin_amdgcn_mfma_f32_16x16x32_bf16(wa0, x00, acc10, 0, 0, 0);
      acc11 = __builtin_amdgcn_mfma_f32_16x16x32_bf16(wa0, x10, acc11, 0, 0, 0);
      bf16x8 x01 = *(const bf16x8*)&xa[m][q * 8 + 32];
      bf16x8 x11 = *(const bf16x8*)&xa[16 + m][q * 8 + 32];
      acc10 = __builtin_amdgcn_mfma_f32_16x16x32_bf16(wa1, x01, acc10, 0, 0, 0);
      acc11 = __builtin_amdgcn_mfma_f32_16x16x32_bf16(wa1, x11, acc11, 0, 0, 0);
      {
        float v0 = acc10[0] * ds0 + b4.x;
        float v1 = acc10[1] * ds0 + b4.y;
        float v2 = acc10[2] * ds0 + b4.z;
        float v3 = acc10[3] * ds0 + b4.w;
        ushort4 o;
        o.x = f2bf(1.f / (1.f + __expf(-v0)));
        o.y = f2bf(1.f / (1.f + __expf(-v1)));
        o.z = f2bf(1.f / (1.f + __expf(-v2)));
        o.w = f2bf(1.f / (1.f + __expf(-v3)));
        *(ushort4*)&fst[m][16 * w + 4 * q] = o;
      }
      {
        float v0 = acc11[0] * ds1 + b4.x;
        float v1 = acc11[1] * ds1 + b4.y;
        float v2 = acc11[2] * ds1 + b4.z;
        float v3 = acc11[3] * ds1 + b4.w;
        ushort4 o;
        o.x = f2bf(1.f / (1.f + __expf(-v0)));
        o.y = f2bf(1.f / (1.f + __expf(-v1)));
        o.z = f2bf(1.f / (1.f + __expf(-v2)));
        o.w = f2bf(1.f / (1.f + __expf(-v3)));
        *(ushort4*)&fst[16 + m][16 * w + 4 * q] = o;
      }
    }
    __syncthreads();

    // stage2 (natural): D[row][oc] -> relu -> full-line stores
    {
      f32x4 a00 = {0, 0, 0, 0}, a01 = {0, 0, 0, 0};
      f32x4 a10 = {0, 0, 0, 0}, a11 = {0, 0, 0, 0};
      bf16x8 f00 = *(const bf16x8*)&fst[m][q * 8];
      bf16x8 f10 = *(const bf16x8*)&fst[16 + m][q * 8];
      a00 = __builtin_amdgcn_mfma_f32_16x16x32_bf16(f00, wb00, a00, 0, 0, 0);
      a10 = __builtin_amdgcn_mfma_f32_16x16x32_bf16(f00, wb10, a10, 0, 0, 0);
      a01 = __builtin_amdgcn_mfma_f32_16x16x32_bf16(f10, wb00, a01, 0, 0, 0);
      a11 = __builtin_amdgcn_mfma_f32_16x16x32_bf16(f10, wb10, a11, 0, 0, 0);
      bf16x8 f01 = *(const bf16x8*)&fst[m][q * 8 + 32];
      bf16x8 f11 = *(const bf16x8*)&fst[16 + m][q * 8 + 32];
      a00 = __builtin_amdgcn_mfma_f32_16x16x32_bf16(f01, wb01, a00, 0, 0, 0);
      a10 = __builtin_amdgcn_mfma_f32_16x16x32_bf16(f01, wb11, a10, 0, 0, 0);
      a01 = __builtin_amdgcn_mfma_f32_16x16x32_bf16(f11, wb01, a01, 0, 0, 0);
      a11 = __builtin_amdgcn_mfma_f32_16x16x32_bf16(f11, wb11, a11, 0, 0, 0);

#pragma unroll
      for (int mt = 0; mt < 2; ++mt)
#pragma unroll
        for (int nt = 0; nt < 2; ++nt) {
          f32x4 acc = mt == 0 ? (nt == 0 ? a00 : a01) : (nt == 0 ? a10 : a11);
#pragma unroll
          for (int r = 0; r < 4; ++r) {
            int row = 16 * nt + 4 * q + r;
            int n = n0 + (row >> 2), b = row & 3;
            float v = acc[r];
            __builtin_nontemporal_store(
                v > 0.f ? v : 0.f,
                out + ((size_t)b * NODES + n) * 128 + 32 * w + 16 * mt + m);
          }
        }
    }
    __syncthreads();  // protect fst/xa reuse across group iterations
  }
}

extern "C" void kernel_launch(void* const* d_in, const int* in_sizes, int n_in,
                              void* d_out, int out_size, void* d_ws, size_t ws_size,
                              hipStream_t stream) {
  const float* x     = (const float*)d_in[0];
  const int*   ei    = (const int*)d_in[1];
  const float* lin_w = (const float*)d_in[2];
  const float* bias  = (const float*)d_in[3];
  const float* up1   = (const float*)d_in[4];
  const float* up2   = (const float*)d_in[5];
  const float* lo1   = (const float*)d_in[6];
  const float* lo2   = (const float*)d_in[7];
  const float* lastw = (const float*)d_in[8];
  float* out = (float*)d_out;

  char* ws = (char*)d_ws;
  unsigned short* wb16 = (unsigned short*)(ws);            // 24576 B
  float* dis        = (float*)(ws + (64 << 10));           // 80 KB
  int*   cnt        = (int*)(ws + (192 << 10));            // 80 KB
  int*   csr        = (int*)(ws + (1 << 20));              // NODES*CAP*4 = 5.12 MB
  unsigned int* xs8 = (unsigned int*)(ws + (8 << 20));     // NODES*256 B = 5.12 MB

  static int grid_blocks = 0;
  if (grid_blocks == 0) {
    int nb = 0;
    (void)hipOccupancyMaxActiveBlocksPerMultiprocessor(&nb, k_all, 256, 0);
    if (nb < 1) nb = 1;
    grid_blocks = nb * 256;  // 256 CUs on MI355X
    if (grid_blocks > NGRP) grid_blocks = NGRP;
    if (grid_blocks < 64) grid_blocks = 64;  // >= LINB+BIGB for weight prep
  }

  void* args[] = {
      (void*)&x, (void*)&ei, (void*)&lin_w, (void*)&bias,
      (void*)&up1, (void*)&up2, (void*)&lo1, (void*)&lo2,
      (void*)&lastw, (void*)&out, (void*)&cnt, (void*)&csr,
      (void*)&xs8, (void*)&dis, (void*)&wb16};
  (void)hipLaunchCooperativeKernel((void*)k_all, dim3(grid_blocks), dim3(256),
                                   args, 0, stream);
}

// Round 4
// 238.136 us; speedup vs baseline: 1.3923x; 1.3923x over previous
//
#include <hip/hip_runtime.h>
#include <cstdint>
#include <cstddef>

#define NODES 20000
#define NEDGE 320000
#define CAP 64            // padded CSR capacity per node (max deg ~34 at 16+/-4)
#define NEB 625           // NEDGE/(256*2) -- 2 edges per thread
#define LINB 16           // 4096/256
#define BIGB 32           // 8192/256

using bf16x8 = __attribute__((ext_vector_type(8))) __bf16;
using f32x4  = __attribute__((ext_vector_type(4))) float;
using f32x2  = __attribute__((ext_vector_type(2))) float;
using i32x4  = __attribute__((ext_vector_type(4))) int;

__device__ __forceinline__ unsigned short f2bf(float f) {
  union { float f; unsigned int u; } v; v.f = f;
  unsigned int r = v.u + 0x7FFF + ((v.u >> 16) & 1);  // RNE
  return (unsigned short)(r >> 16);
}

#define DECACC(u, s0, s1, s2, s3)                               \
  {                                                             \
    f32x2 lo_ = __builtin_amdgcn_cvt_pk_f32_fp8(u, false);      \
    f32x2 hi_ = __builtin_amdgcn_cvt_pk_f32_fp8(u, true);       \
    s0 += lo_.x; s1 += lo_.y; s2 += hi_.x; s3 += hi_.y;         \
  }

// ---------------- build: padded-CSR fill + lin->bf16 + BigW (direct) ----------------
__global__ void k_build(const int* __restrict__ ei, int* __restrict__ cnt,
                        int* __restrict__ csr,
                        const float* __restrict__ lin, const float* __restrict__ u1,
                        const float* __restrict__ u2, const float* __restrict__ l1,
                        const float* __restrict__ l2, const float* __restrict__ lastw,
                        unsigned short* __restrict__ wb16) {
  __shared__ float tmp_u[4][64];
  __shared__ float tmp_l[4][64];
  int bid = blockIdx.x, t = threadIdx.x;
  if (bid < NEB) {
    int i = (bid * 256 + t) * 2;          // 625*256*2 == NEDGE exactly
    int2 r2 = *(const int2*)(ei + i);
    int2 c2 = *(const int2*)(ei + NEDGE + i);
    int p0 = atomicAdd(&cnt[c2.x], 1);
    if (p0 < CAP) csr[c2.x * CAP + p0] = r2.x;
    int p1 = atomicAdd(&cnt[c2.y], 1);
    if (p1 < CAP) csr[c2.y * CAP + p1] = r2.y;
  } else if (bid < NEB + LINB) {
    int g = (bid - NEB) * 256 + t;  // [0,4096)
    wb16[g] = f2bf(lin[g]);
  } else {
    int o0 = (bid - NEB - LINB) * 4;
    int ol = t >> 6, p = t & 63;
    float su = 0.f, sl = 0.f;
    for (int k = 0; k < 64; ++k) {
      float lu = lastw[(o0 + ol) * 128 + k];
      float ll = lastw[(o0 + ol) * 128 + 64 + k];
      su += lu * u2[k * 64 + p];
      sl += ll * l2[k * 64 + p];
    }
    tmp_u[ol][p] = su;
    tmp_l[ol][p] = sl;
    __syncthreads();
    int j = p;
    float acc = 0.f;
    for (int q = 0; q < 64; ++q)
      acc += tmp_u[ol][q] * u1[q * 64 + j] + tmp_l[ol][q] * l1[q * 64 + j];
    wb16[4096 + (o0 + ol) * 64 + j] = f2bf(acc);
  }
}

// ---------------- xconv: dis = rsqrt(cnt+1); xs8 = fp8(x * dis) ----------------
__global__ void k_xconv(const int* __restrict__ cnt, float* __restrict__ dis,
                        const float* __restrict__ x, unsigned int* __restrict__ xs8) {
  int g = blockIdx.x * 256 + threadIdx.x;  // [0, NODES*64)
  int n = g >> 6, i = g & 63;
  int b = i >> 4, c = (i & 15) * 4;
  float ds = rsqrtf((float)(cnt[n] + 1));  // +1 = self loop
  if (i == 0) dis[n] = ds;
  f32x4 v = __builtin_nontemporal_load(
      (const f32x4*)(x + ((size_t)b * NODES + n) * 64 + c));
  int p = 0;
  p = __builtin_amdgcn_cvt_pk_fp8_f32(v.x * ds, v.y * ds, p, false);  // bytes 0,1
  p = __builtin_amdgcn_cvt_pk_fp8_f32(v.z * ds, v.w * ds, p, true);   // bytes 2,3
  xs8[(size_t)n * 64 + i] = (unsigned int)p;
}

// ---------------- fused gather(fp8) + lin + sigmoid + BigW + relu ----------------
__global__ __launch_bounds__(256) void k_gpost(const int* __restrict__ cnt,
                                               const int* __restrict__ csr,
                                               const unsigned int* __restrict__ xs8,
                                               const float* __restrict__ dis,
                                               const float* __restrict__ bias,
                                               const unsigned short* __restrict__ wb16,
                                               float* __restrict__ out) {
  __shared__ unsigned short xa[32][72];
  __shared__ unsigned short fst[32][72];
  int t = threadIdx.x;
  int w = t >> 6, l = t & 63;
  int n0 = blockIdx.x * 8;
  int nA = n0 + 2 * w;  // wave handles nodes nA, nA+1, interleaved

  int2 cc = *(const int2*)(cnt + nA);
  int dA = cc.x > CAP ? CAP : cc.x;
  int dB = cc.y > CAP ? CAP : cc.y;

  float aA0, aA1, aA2, aA3, aB0, aB1, aB2, aB3;
  {
    unsigned int uA = xs8[(size_t)nA * 64 + l];        // self loop A
    unsigned int uB = xs8[(size_t)(nA + 1) * 64 + l];  // self loop B
    f32x2 lo = __builtin_amdgcn_cvt_pk_f32_fp8(uA, false);
    f32x2 hi = __builtin_amdgcn_cvt_pk_f32_fp8(uA, true);
    aA0 = lo.x; aA1 = lo.y; aA2 = hi.x; aA3 = hi.y;
    lo = __builtin_amdgcn_cvt_pk_f32_fp8(uB, false);
    hi = __builtin_amdgcn_cvt_pk_f32_fp8(uB, true);
    aB0 = lo.x; aB1 = lo.y; aB2 = hi.x; aB3 = hi.y;
  }

  int iA = nA * CAP, eA = iA + dA;
  int iB = iA + CAP, eB = iB + dB;

  while (iA + 8 <= eA && iB + 8 <= eB) {
    i32x4 ra0 = __builtin_nontemporal_load((const i32x4*)(csr + iA));
    i32x4 ra1 = __builtin_nontemporal_load((const i32x4*)(csr + iA + 4));
    i32x4 rb0 = __builtin_nontemporal_load((const i32x4*)(csr + iB));
    i32x4 rb1 = __builtin_nontemporal_load((const i32x4*)(csr + iB + 4));
    unsigned int uA0 = xs8[(size_t)ra0.x * 64 + l];
    unsigned int uA1 = xs8[(size_t)ra0.y * 64 + l];
    unsigned int uA2 = xs8[(size_t)ra0.z * 64 + l];
    unsigned int uA3 = xs8[(size_t)ra0.w * 64 + l];
    unsigned int uA4 = xs8[(size_t)ra1.x * 64 + l];
    unsigned int uA5 = xs8[(size_t)ra1.y * 64 + l];
    unsigned int uA6 = xs8[(size_t)ra1.z * 64 + l];
    unsigned int uA7 = xs8[(size_t)ra1.w * 64 + l];
    unsigned int uB0 = xs8[(size_t)rb0.x * 64 + l];
    unsigned int uB1 = xs8[(size_t)rb0.y * 64 + l];
    unsigned int uB2 = xs8[(size_t)rb0.z * 64 + l];
    unsigned int uB3 = xs8[(size_t)rb0.w * 64 + l];
    unsigned int uB4 = xs8[(size_t)rb1.x * 64 + l];
    unsigned int uB5 = xs8[(size_t)rb1.y * 64 + l];
    unsigned int uB6 = xs8[(size_t)rb1.z * 64 + l];
    unsigned int uB7 = xs8[(size_t)rb1.w * 64 + l];
    DECACC(uA0, aA0, aA1, aA2, aA3); DECACC(uA1, aA0, aA1, aA2, aA3);
    DECACC(uA2, aA0, aA1, aA2, aA3); DECACC(uA3, aA0, aA1, aA2, aA3);
    DECACC(uA4, aA0, aA1, aA2, aA3); DECACC(uA5, aA0, aA1, aA2, aA3);
    DECACC(uA6, aA0, aA1, aA2, aA3); DECACC(uA7, aA0, aA1, aA2, aA3);
    DECACC(uB0, aB0, aB1, aB2, aB3); DECACC(uB1, aB0, aB1, aB2, aB3);
    DECACC(uB2, aB0, aB1, aB2, aB3); DECACC(uB3, aB0, aB1, aB2, aB3);
    DECACC(uB4, aB0, aB1, aB2, aB3); DECACC(uB5, aB0, aB1, aB2, aB3);
    DECACC(uB6, aB0, aB1, aB2, aB3); DECACC(uB7, aB0, aB1, aB2, aB3);
    iA += 8; iB += 8;
  }
  while (iA + 8 <= eA) {
    i32x4 r0 = __builtin_nontemporal_load((const i32x4*)(csr + iA));
    i32x4 r1 = __builtin_nontemporal_load((const i32x4*)(csr + iA + 4));
    unsigned int u0 = xs8[(size_t)r0.x * 64 + l];
    unsigned int u1 = xs8[(size_t)r0.y * 64 + l];
    unsigned int u2 = xs8[(size_t)r0.z * 64 + l];
    unsigned int u3 = xs8[(size_t)r0.w * 64 + l];
    unsigned int u4 = xs8[(size_t)r1.x * 64 + l];
    unsigned int u5 = xs8[(size_t)r1.y * 64 + l];
    unsigned int u6 = xs8[(size_t)r1.z * 64 + l];
    unsigned int u7 = xs8[(size_t)r1.w * 64 + l];
    DECACC(u0, aA0, aA1, aA2, aA3); DECACC(u1, aA0, aA1, aA2, aA3);
    DECACC(u2, aA0, aA1, aA2, aA3); DECACC(u3, aA0, aA1, aA2, aA3);
    DECACC(u4, aA0, aA1, aA2, aA3); DECACC(u5, aA0, aA1, aA2, aA3);
    DECACC(u6, aA0, aA1, aA2, aA3); DECACC(u7, aA0, aA1, aA2, aA3);
    iA += 8;
  }
  while (iB + 8 <= eB) {
    i32x4 r0 = __builtin_nontemporal_load((const i32x4*)(csr + iB));
    i32x4 r1 = __builtin_nontemporal_load((const i32x4*)(csr + iB + 4));
    unsigned int u0 = xs8[(size_t)r0.x * 64 + l];
    unsigned int u1 = xs8[(size_t)r0.y * 64 + l];
    unsigned int u2 = xs8[(size_t)r0.z * 64 + l];
    unsigned int u3 = xs8[(size_t)r0.w * 64 + l];
    unsigned int u4 = xs8[(size_t)r1.x * 64 + l];
    unsigned int u5 = xs8[(size_t)r1.y * 64 + l];
    unsigned int u6 = xs8[(size_t)r1.z * 64 + l];
    unsigned int u7 = xs8[(size_t)r1.w * 64 + l];
    DECACC(u0, aB0, aB1, aB2, aB3); DECACC(u1, aB0, aB1, aB2, aB3);
    DECACC(u2, aB0, aB1, aB2, aB3); DECACC(u3, aB0, aB1, aB2, aB3);
    DECACC(u4, aB0, aB1, aB2, aB3); DECACC(u5, aB0, aB1, aB2, aB3);
    DECACC(u6, aB0, aB1, aB2, aB3); DECACC(u7, aB0, aB1, aB2, aB3);
    iB += 8;
  }
  while (iA + 4 <= eA) {
    i32x4 r0 = __builtin_nontemporal_load((const i32x4*)(csr + iA));
    unsigned int u0 = xs8[(size_t)r0.x * 64 + l];
    unsigned int u1 = xs8[(size_t)r0.y * 64 + l];
    unsigned int u2 = xs8[(size_t)r0.z * 64 + l];
    unsigned int u3 = xs8[(size_t)r0.w * 64 + l];
    DECACC(u0, aA0, aA1, aA2, aA3); DECACC(u1, aA0, aA1, aA2, aA3);
    DECACC(u2, aA0, aA1, aA2, aA3); DECACC(u3, aA0, aA1, aA2, aA3);
    iA += 4;
  }
  while (iB + 4 <= eB) {
    i32x4 r0 = __builtin_nontemporal_load((const i32x4*)(csr + iB));
    unsigned int u0 = xs8[(size_t)r0.x * 64 + l];
    unsigned int u1 = xs8[(size_t)r0.y * 64 + l];
    unsigned int u2 = xs8[(size_t)r0.z * 64 + l];
    unsigned int u3 = xs8[(size_t)r0.w * 64 + l];
    DECACC(u0, aB0, aB1, aB2, aB3); DECACC(u1, aB0, aB1, aB2, aB3);
    DECACC(u2, aB0, aB1, aB2, aB3); DECACC(u3, aB0, aB1, aB2, aB3);
    iB += 4;
  }
  for (; iA < eA; ++iA) {
    unsigned int u = xs8[(size_t)csr[iA] * 64 + l];
    DECACC(u, aA0, aA1, aA2, aA3);
  }
  for (; iB < eB; ++iB) {
    unsigned int u = xs8[(size_t)csr[iB] * 64 + l];
    DECACC(u, aB0, aB1, aB2, aB3);
  }

  {
    ushort4 o;
    o.x = f2bf(aA0); o.y = f2bf(aA1); o.z = f2bf(aA2); o.w = f2bf(aA3);
    *(ushort4*)&xa[(2 * w) * 4 + (l >> 4)][(l & 15) * 4] = o;
    o.x = f2bf(aB0); o.y = f2bf(aB1); o.z = f2bf(aB2); o.w = f2bf(aB3);
    *(ushort4*)&xa[(2 * w + 1) * 4 + (l >> 4)][(l & 15) * 4] = o;
  }

  int m = l & 15, q = l >> 4;
  const unsigned short* wlin = wb16;
  const unsigned short* bigw = wb16 + 4096;

  bf16x8 wa0  = *(const bf16x8*)(wlin + (16 * w + m) * 64 + q * 8);
  bf16x8 wa1  = *(const bf16x8*)(wlin + (16 * w + m) * 64 + q * 8 + 32);
  bf16x8 wb00 = *(const bf16x8*)(bigw + (32 * w + m) * 64 + q * 8);
  bf16x8 wb10 = *(const bf16x8*)(bigw + (32 * w + 16 + m) * 64 + q * 8);
  bf16x8 wb01 = *(const bf16x8*)(bigw + (32 * w + m) * 64 + q * 8 + 32);
  bf16x8 wb11 = *(const bf16x8*)(bigw + (32 * w + 16 + m) * 64 + q * 8 + 32);
  float4 b4 = *(const float4*)(bias + 16 * w + 4 * q);
  float ds0 = dis[n0 + (m >> 2)];
  float ds1 = dis[n0 + 4 + (m >> 2)];

  __syncthreads();

  {
    f32x4 acc10 = {0, 0, 0, 0}, acc11 = {0, 0, 0, 0};
    bf16x8 x00 = *(const bf16x8*)&xa[m][q * 8];
    bf16x8 x10 = *(const bf16x8*)&xa[16 + m][q * 8];
    acc10 = __builtin_amdgcn_mfma_f32_16x16x32_bf16(wa0, x00, acc10, 0, 0, 0);
    acc11 = __builtin_amdgcn_mfma_f32_16x16x32_bf16(wa0, x10, acc11, 0, 0, 0);
    bf16x8 x01 = *(const bf16x8*)&xa[m][q * 8 + 32];
    bf16x8 x11 = *(const bf16x8*)&xa[16 + m][q * 8 + 32];
    acc10 = __builtin_amdgcn_mfma_f32_16x16x32_bf16(wa1, x01, acc10, 0, 0, 0);
    acc11 = __builtin_amdgcn_mfma_f32_16x16x32_bf16(wa1, x11, acc11, 0, 0, 0);
    {
      float v0 = acc10[0] * ds0 + b4.x;
      float v1 = acc10[1] * ds0 + b4.y;
      float v2 = acc10[2] * ds0 + b4.z;
      float v3 = acc10[3] * ds0 + b4.w;
      ushort4 o;
      o.x = f2bf(1.f / (1.f + __expf(-v0)));
      o.y = f2bf(1.f / (1.f + __expf(-v1)));
      o.z = f2bf(1.f / (1.f + __expf(-v2)));
      o.w = f2bf(1.f / (1.f + __expf(-v3)));
      *(ushort4*)&fst[m][16 * w + 4 * q] = o;
    }
    {
      float v0 = acc11[0] * ds1 + b4.x;
      float v1 = acc11[1] * ds1 + b4.y;
      float v2 = acc11[2] * ds1 + b4.z;
      float v3 = acc11[3] * ds1 + b4.w;
      ushort4 o;
      o.x = f2bf(1.f / (1.f + __expf(-v0)));
      o.y = f2bf(1.f / (1.f + __expf(-v1)));
      o.z = f2bf(1.f / (1.f + __expf(-v2)));
      o.w = f2bf(1.f / (1.f + __expf(-v3)));
      *(ushort4*)&fst[16 + m][16 * w + 4 * q] = o;
    }
  }
  __syncthreads();

  {
    f32x4 a00 = {0, 0, 0, 0}, a01 = {0, 0, 0, 0};
    f32x4 a10 = {0, 0, 0, 0}, a11 = {0, 0, 0, 0};
    bf16x8 f00 = *(const bf16x8*)&fst[m][q * 8];
    bf16x8 f10 = *(const bf16x8*)&fst[16 + m][q * 8];
    a00 = __builtin_amdgcn_mfma_f32_16x16x32_bf16(f00, wb00, a00, 0, 0, 0);
    a10 = __builtin_amdgcn_mfma_f32_16x16x32_bf16(f00, wb10, a10, 0, 0, 0);
    a01 = __builtin_amdgcn_mfma_f32_16x16x32_bf16(f10, wb00, a01, 0, 0, 0);
    a11 = __builtin_amdgcn_mfma_f32_16x16x32_bf16(f10, wb10, a11, 0, 0, 0);
    bf16x8 f01 = *(const bf16x8*)&fst[m][q * 8 + 32];
    bf16x8 f11 = *(const bf16x8*)&fst[16 + m][q * 8 + 32];
    a00 = __builtin_amdgcn_mfma_f32_16x16x32_bf16(f01, wb01, a00, 0, 0, 0);
    a10 = __builtin_amdgcn_mfma_f32_16x16x32_bf16(f01, wb11, a10, 0, 0, 0);
    a01 = __builtin_amdgcn_mfma_f32_16x16x32_bf16(f11, wb01, a01, 0, 0, 0);
    a11 = __builtin_amdgcn_mfma_f32_16x16x32_bf16(f11, wb11, a11, 0, 0, 0);

#pragma unroll
    for (int mt = 0; mt < 2; ++mt)
#pragma unroll
      for (int nt = 0; nt < 2; ++nt) {
        f32x4 acc = mt == 0 ? (nt == 0 ? a00 : a01) : (nt == 0 ? a10 : a11);
#pragma unroll
        for (int r = 0; r < 4; ++r) {
          int row = 16 * nt + 4 * q + r;
          int n = n0 + (row >> 2), b = row & 3;
          float v = acc[r];
          __builtin_nontemporal_store(
              v > 0.f ? v : 0.f,
              out + ((size_t)b * NODES + n) * 128 + 32 * w + 16 * mt + m);
        }
      }
  }
}

extern "C" void kernel_launch(void* const* d_in, const int* in_sizes, int n_in,
                              void* d_out, int out_size, void* d_ws, size_t ws_size,
                              hipStream_t stream) {
  const float* x     = (const float*)d_in[0];
  const int*   ei    = (const int*)d_in[1];
  const float* lin_w = (const float*)d_in[2];
  const float* bias  = (const float*)d_in[3];
  const float* up1   = (const float*)d_in[4];
  const float* up2   = (const float*)d_in[5];
  const float* lo1   = (const float*)d_in[6];
  const float* lo2   = (const float*)d_in[7];
  const float* lastw = (const float*)d_in[8];
  float* out = (float*)d_out;

  char* ws = (char*)d_ws;
  unsigned short* wb16 = (unsigned short*)(ws);            // 24576 B
  float* dis        = (float*)(ws + (64 << 10));           // 80 KB
  int*   cnt        = (int*)(ws + (192 << 10));            // 80 KB
  int*   csr        = (int*)(ws + (1 << 20));              // NODES*CAP*4 = 5.12 MB
  unsigned int* xs8 = (unsigned int*)(ws + (8 << 20));     // NODES*256 B = 5.12 MB

  (void)hipMemsetAsync(cnt, 0, NODES * sizeof(int), stream);
  k_build<<<NEB + LINB + BIGB, 256, 0, stream>>>(ei, cnt, csr, lin_w, up1, up2,
                                                 lo1, lo2, lastw, wb16);
  k_xconv<<<NODES / 4, 256, 0, stream>>>(cnt, dis, x, xs8);
  // MEASUREMENT: k_gpost is idempotent (same inputs -> same out values).
  // Launch 4x; dur_us_new - dur_us_old = 3 * t_gpost (+3 gaps).
  k_gpost<<<NODES / 8, 256, 0, stream>>>(cnt, csr, xs8, dis, bias, wb16, out);
  k_gpost<<<NODES / 8, 256, 0, stream>>>(cnt, csr, xs8, dis, bias, wb16, out);
  k_gpost<<<NODES / 8, 256, 0, stream>>>(cnt, csr, xs8, dis, bias, wb16, out);
  k_gpost<<<NODES / 8, 256, 0, stream>>>(cnt, csr, xs8, dis, bias, wb16, out);
}

// Round 5
// 209.409 us; speedup vs baseline: 1.5833x; 1.1372x over previous
//
#include <hip/hip_runtime.h>
#include <cstdint>
#include <cstddef>

#define NODES 20000
#define NEDGE 320000
#define CAP 64            // padded CSR capacity per node (max deg ~34 at 16+/-4)
#define NEB 625           // NEDGE/(256*2) -- 2 edges per thread
#define LINB 16           // 4096/256
#define BIGB 32           // 8192/256

using bf16x8 = __attribute__((ext_vector_type(8))) __bf16;
using f32x4  = __attribute__((ext_vector_type(4))) float;
using f32x2  = __attribute__((ext_vector_type(2))) float;
using i32x4  = __attribute__((ext_vector_type(4))) int;

__device__ __forceinline__ unsigned short f2bf(float f) {
  union { float f; unsigned int u; } v; v.f = f;
  unsigned int r = v.u + 0x7FFF + ((v.u >> 16) & 1);  // RNE
  return (unsigned short)(r >> 16);
}

#define DECACC(u, s0, s1, s2, s3)                               \
  {                                                             \
    f32x2 lo_ = __builtin_amdgcn_cvt_pk_f32_fp8(u, false);      \
    f32x2 hi_ = __builtin_amdgcn_cvt_pk_f32_fp8(u, true);       \
    s0 += lo_.x; s1 += lo_.y; s2 += hi_.x; s3 += hi_.y;         \
  }

// ---------------- build: padded-CSR fill + lin->bf16 + BigW (direct) ----------------
__global__ void k_build(const int* __restrict__ ei, int* __restrict__ cnt,
                        int* __restrict__ csr,
                        const float* __restrict__ lin, const float* __restrict__ u1,
                        const float* __restrict__ u2, const float* __restrict__ l1,
                        const float* __restrict__ l2, const float* __restrict__ lastw,
                        unsigned short* __restrict__ wb16) {
  __shared__ float tmp_u[4][64];
  __shared__ float tmp_l[4][64];
  int bid = blockIdx.x, t = threadIdx.x;
  if (bid < NEB) {
    int i = (bid * 256 + t) * 2;          // 625*256*2 == NEDGE exactly
    int2 r2 = *(const int2*)(ei + i);
    int2 c2 = *(const int2*)(ei + NEDGE + i);
    int p0 = atomicAdd(&cnt[c2.x], 1);
    if (p0 < CAP) csr[c2.x * CAP + p0] = r2.x;
    int p1 = atomicAdd(&cnt[c2.y], 1);
    if (p1 < CAP) csr[c2.y * CAP + p1] = r2.y;
  } else if (bid < NEB + LINB) {
    int g = (bid - NEB) * 256 + t;  // [0,4096)
    wb16[g] = f2bf(lin[g]);
  } else {
    int o0 = (bid - NEB - LINB) * 4;
    int ol = t >> 6, p = t & 63;
    float su = 0.f, sl = 0.f;
    for (int k = 0; k < 64; ++k) {
      float lu = lastw[(o0 + ol) * 128 + k];
      float ll = lastw[(o0 + ol) * 128 + 64 + k];
      su += lu * u2[k * 64 + p];
      sl += ll * l2[k * 64 + p];
    }
    tmp_u[ol][p] = su;
    tmp_l[ol][p] = sl;
    __syncthreads();
    int j = p;
    float acc = 0.f;
    for (int q = 0; q < 64; ++q)
      acc += tmp_u[ol][q] * u1[q * 64 + j] + tmp_l[ol][q] * l1[q * 64 + j];
    wb16[4096 + (o0 + ol) * 64 + j] = f2bf(acc);
  }
}

// ---------------- xconv: dis = rsqrt(cnt+1); xs8 = fp8(x * dis) ----------------
__global__ void k_xconv(const int* __restrict__ cnt, float* __restrict__ dis,
                        const float* __restrict__ x, unsigned int* __restrict__ xs8) {
  int g = blockIdx.x * 256 + threadIdx.x;  // [0, NODES*64)
  int n = g >> 6, i = g & 63;
  int b = i >> 4, c = (i & 15) * 4;
  float ds = rsqrtf((float)(cnt[n] + 1));  // +1 = self loop
  if (i == 0) dis[n] = ds;
  f32x4 v = __builtin_nontemporal_load(
      (const f32x4*)(x + ((size_t)b * NODES + n) * 64 + c));
  int p = 0;
  p = __builtin_amdgcn_cvt_pk_fp8_f32(v.x * ds, v.y * ds, p, false);  // bytes 0,1
  p = __builtin_amdgcn_cvt_pk_fp8_f32(v.z * ds, v.w * ds, p, true);   // bytes 2,3
  xs8[(size_t)n * 64 + i] = (unsigned int)p;
}

// ---------------- fused gather(fp8) + lin + sigmoid + BigW + relu ----------------
__global__ __launch_bounds__(256) void k_gpost(const int* __restrict__ cnt,
                                               const int* __restrict__ csr,
                                               const unsigned int* __restrict__ xs8,
                                               const float* __restrict__ dis,
                                               const float* __restrict__ bias,
                                               const unsigned short* __restrict__ wb16,
                                               float* __restrict__ out) {
  __shared__ unsigned short xa[32][72];
  __shared__ unsigned short fst[32][72];
  int t = threadIdx.x;
  int w = t >> 6, l = t & 63;
  int n0 = blockIdx.x * 8;
  int nA = n0 + 2 * w;  // wave handles nodes nA, nA+1, interleaved

  int2 cc = *(const int2*)(cnt + nA);
  int dA = cc.x > CAP ? CAP : cc.x;
  int dB = cc.y > CAP ? CAP : cc.y;

  float aA0, aA1, aA2, aA3, aB0, aB1, aB2, aB3;
  {
    unsigned int uA = xs8[(size_t)nA * 64 + l];        // self loop A
    unsigned int uB = xs8[(size_t)(nA + 1) * 64 + l];  // self loop B
    f32x2 lo = __builtin_amdgcn_cvt_pk_f32_fp8(uA, false);
    f32x2 hi = __builtin_amdgcn_cvt_pk_f32_fp8(uA, true);
    aA0 = lo.x; aA1 = lo.y; aA2 = hi.x; aA3 = hi.y;
    lo = __builtin_amdgcn_cvt_pk_f32_fp8(uB, false);
    hi = __builtin_amdgcn_cvt_pk_f32_fp8(uB, true);
    aB0 = lo.x; aB1 = lo.y; aB2 = hi.x; aB3 = hi.y;
  }

  int iA = nA * CAP, eA = iA + dA;
  int iB = iA + CAP, eB = iB + dB;

  while (iA + 8 <= eA && iB + 8 <= eB) {
    i32x4 ra0 = __builtin_nontemporal_load((const i32x4*)(csr + iA));
    i32x4 ra1 = __builtin_nontemporal_load((const i32x4*)(csr + iA + 4));
    i32x4 rb0 = __builtin_nontemporal_load((const i32x4*)(csr + iB));
    i32x4 rb1 = __builtin_nontemporal_load((const i32x4*)(csr + iB + 4));
    unsigned int uA0 = xs8[(size_t)ra0.x * 64 + l];
    unsigned int uA1 = xs8[(size_t)ra0.y * 64 + l];
    unsigned int uA2 = xs8[(size_t)ra0.z * 64 + l];
    unsigned int uA3 = xs8[(size_t)ra0.w * 64 + l];
    unsigned int uA4 = xs8[(size_t)ra1.x * 64 + l];
    unsigned int uA5 = xs8[(size_t)ra1.y * 64 + l];
    unsigned int uA6 = xs8[(size_t)ra1.z * 64 + l];
    unsigned int uA7 = xs8[(size_t)ra1.w * 64 + l];
    unsigned int uB0 = xs8[(size_t)rb0.x * 64 + l];
    unsigned int uB1 = xs8[(size_t)rb0.y * 64 + l];
    unsigned int uB2 = xs8[(size_t)rb0.z * 64 + l];
    unsigned int uB3 = xs8[(size_t)rb0.w * 64 + l];
    unsigned int uB4 = xs8[(size_t)rb1.x * 64 + l];
    unsigned int uB5 = xs8[(size_t)rb1.y * 64 + l];
    unsigned int uB6 = xs8[(size_t)rb1.z * 64 + l];
    unsigned int uB7 = xs8[(size_t)rb1.w * 64 + l];
    DECACC(uA0, aA0, aA1, aA2, aA3); DECACC(uA1, aA0, aA1, aA2, aA3);
    DECACC(uA2, aA0, aA1, aA2, aA3); DECACC(uA3, aA0, aA1, aA2, aA3);
    DECACC(uA4, aA0, aA1, aA2, aA3); DECACC(uA5, aA0, aA1, aA2, aA3);
    DECACC(uA6, aA0, aA1, aA2, aA3); DECACC(uA7, aA0, aA1, aA2, aA3);
    DECACC(uB0, aB0, aB1, aB2, aB3); DECACC(uB1, aB0, aB1, aB2, aB3);
    DECACC(uB2, aB0, aB1, aB2, aB3); DECACC(uB3, aB0, aB1, aB2, aB3);
    DECACC(uB4, aB0, aB1, aB2, aB3); DECACC(uB5, aB0, aB1, aB2, aB3);
    DECACC(uB6, aB0, aB1, aB2, aB3); DECACC(uB7, aB0, aB1, aB2, aB3);
    iA += 8; iB += 8;
  }
  while (iA + 8 <= eA) {
    i32x4 r0 = __builtin_nontemporal_load((const i32x4*)(csr + iA));
    i32x4 r1 = __builtin_nontemporal_load((const i32x4*)(csr + iA + 4));
    unsigned int u0 = xs8[(size_t)r0.x * 64 + l];
    unsigned int u1 = xs8[(size_t)r0.y * 64 + l];
    unsigned int u2 = xs8[(size_t)r0.z * 64 + l];
    unsigned int u3 = xs8[(size_t)r0.w * 64 + l];
    unsigned int u4 = xs8[(size_t)r1.x * 64 + l];
    unsigned int u5 = xs8[(size_t)r1.y * 64 + l];
    unsigned int u6 = xs8[(size_t)r1.z * 64 + l];
    unsigned int u7 = xs8[(size_t)r1.w * 64 + l];
    DECACC(u0, aA0, aA1, aA2, aA3); DECACC(u1, aA0, aA1, aA2, aA3);
    DECACC(u2, aA0, aA1, aA2, aA3); DECACC(u3, aA0, aA1, aA2, aA3);
    DECACC(u4, aA0, aA1, aA2, aA3); DECACC(u5, aA0, aA1, aA2, aA3);
    DECACC(u6, aA0, aA1, aA2, aA3); DECACC(u7, aA0, aA1, aA2, aA3);
    iA += 8;
  }
  while (iB + 8 <= eB) {
    i32x4 r0 = __builtin_nontemporal_load((const i32x4*)(csr + iB));
    i32x4 r1 = __builtin_nontemporal_load((const i32x4*)(csr + iB + 4));
    unsigned int u0 = xs8[(size_t)r0.x * 64 + l];
    unsigned int u1 = xs8[(size_t)r0.y * 64 + l];
    unsigned int u2 = xs8[(size_t)r0.z * 64 + l];
    unsigned int u3 = xs8[(size_t)r0.w * 64 + l];
    unsigned int u4 = xs8[(size_t)r1.x * 64 + l];
    unsigned int u5 = xs8[(size_t)r1.y * 64 + l];
    unsigned int u6 = xs8[(size_t)r1.z * 64 + l];
    unsigned int u7 = xs8[(size_t)r1.w * 64 + l];
    DECACC(u0, aB0, aB1, aB2, aB3); DECACC(u1, aB0, aB1, aB2, aB3);
    DECACC(u2, aB0, aB1, aB2, aB3); DECACC(u3, aB0, aB1, aB2, aB3);
    DECACC(u4, aB0, aB1, aB2, aB3); DECACC(u5, aB0, aB1, aB2, aB3);
    DECACC(u6, aB0, aB1, aB2, aB3); DECACC(u7, aB0, aB1, aB2, aB3);
    iB += 8;
  }
  while (iA + 4 <= eA) {
    i32x4 r0 = __builtin_nontemporal_load((const i32x4*)(csr + iA));
    unsigned int u0 = xs8[(size_t)r0.x * 64 + l];
    unsigned int u1 = xs8[(size_t)r0.y * 64 + l];
    unsigned int u2 = xs8[(size_t)r0.z * 64 + l];
    unsigned int u3 = xs8[(size_t)r0.w * 64 + l];
    DECACC(u0, aA0, aA1, aA2, aA3); DECACC(u1, aA0, aA1, aA2, aA3);
    DECACC(u2, aA0, aA1, aA2, aA3); DECACC(u3, aA0, aA1, aA2, aA3);
    iA += 4;
  }
  while (iB + 4 <= eB) {
    i32x4 r0 = __builtin_nontemporal_load((const i32x4*)(csr + iB));
    unsigned int u0 = xs8[(size_t)r0.x * 64 + l];
    unsigned int u1 = xs8[(size_t)r0.y * 64 + l];
    unsigned int u2 = xs8[(size_t)r0.z * 64 + l];
    unsigned int u3 = xs8[(size_t)r0.w * 64 + l];
    DECACC(u0, aB0, aB1, aB2, aB3); DECACC(u1, aB0, aB1, aB2, aB3);
    DECACC(u2, aB0, aB1, aB2, aB3); DECACC(u3, aB0, aB1, aB2, aB3);
    iB += 4;
  }
  for (; iA < eA; ++iA) {
    unsigned int u = xs8[(size_t)csr[iA] * 64 + l];
    DECACC(u, aA0, aA1, aA2, aA3);
  }
  for (; iB < eB; ++iB) {
    unsigned int u = xs8[(size_t)csr[iB] * 64 + l];
    DECACC(u, aB0, aB1, aB2, aB3);
  }

  {
    ushort4 o;
    o.x = f2bf(aA0); o.y = f2bf(aA1); o.z = f2bf(aA2); o.w = f2bf(aA3);
    *(ushort4*)&xa[(2 * w) * 4 + (l >> 4)][(l & 15) * 4] = o;
    o.x = f2bf(aB0); o.y = f2bf(aB1); o.z = f2bf(aB2); o.w = f2bf(aB3);
    *(ushort4*)&xa[(2 * w + 1) * 4 + (l >> 4)][(l & 15) * 4] = o;
  }

  int m = l & 15, q = l >> 4;
  const unsigned short* wlin = wb16;
  const unsigned short* bigw = wb16 + 4096;

  bf16x8 wa0  = *(const bf16x8*)(wlin + (16 * w + m) * 64 + q * 8);
  bf16x8 wa1  = *(const bf16x8*)(wlin + (16 * w + m) * 64 + q * 8 + 32);
  bf16x8 wb00 = *(const bf16x8*)(bigw + (32 * w + m) * 64 + q * 8);
  bf16x8 wb10 = *(const bf16x8*)(bigw + (32 * w + 16 + m) * 64 + q * 8);
  bf16x8 wb01 = *(const bf16x8*)(bigw + (32 * w + m) * 64 + q * 8 + 32);
  bf16x8 wb11 = *(const bf16x8*)(bigw + (32 * w + 16 + m) * 64 + q * 8 + 32);
  float4 b4 = *(const float4*)(bias + 16 * w + 4 * q);
  float ds0 = dis[n0 + (m >> 2)];
  float ds1 = dis[n0 + 4 + (m >> 2)];

  __syncthreads();

  {
    f32x4 acc10 = {0, 0, 0, 0}, acc11 = {0, 0, 0, 0};
    bf16x8 x00 = *(const bf16x8*)&xa[m][q * 8];
    bf16x8 x10 = *(const bf16x8*)&xa[16 + m][q * 8];
    acc10 = __builtin_amdgcn_mfma_f32_16x16x32_bf16(wa0, x00, acc10, 0, 0, 0);
    acc11 = __builtin_amdgcn_mfma_f32_16x16x32_bf16(wa0, x10, acc11, 0, 0, 0);
    bf16x8 x01 = *(const bf16x8*)&xa[m][q * 8 + 32];
    bf16x8 x11 = *(const bf16x8*)&xa[16 + m][q * 8 + 32];
    acc10 = __builtin_amdgcn_mfma_f32_16x16x32_bf16(wa1, x01, acc10, 0, 0, 0);
    acc11 = __builtin_amdgcn_mfma_f32_16x16x32_bf16(wa1, x11, acc11, 0, 0, 0);
    {
      float v0 = acc10[0] * ds0 + b4.x;
      float v1 = acc10[1] * ds0 + b4.y;
      float v2 = acc10[2] * ds0 + b4.z;
      float v3 = acc10[3] * ds0 + b4.w;
      ushort4 o;
      o.x = f2bf(1.f / (1.f + __expf(-v0)));
      o.y = f2bf(1.f / (1.f + __expf(-v1)));
      o.z = f2bf(1.f / (1.f + __expf(-v2)));
      o.w = f2bf(1.f / (1.f + __expf(-v3)));
      *(ushort4*)&fst[m][16 * w + 4 * q] = o;
    }
    {
      float v0 = acc11[0] * ds1 + b4.x;
      float v1 = acc11[1] * ds1 + b4.y;
      float v2 = acc11[2] * ds1 + b4.z;
      float v3 = acc11[3] * ds1 + b4.w;
      ushort4 o;
      o.x = f2bf(1.f / (1.f + __expf(-v0)));
      o.y = f2bf(1.f / (1.f + __expf(-v1)));
      o.z = f2bf(1.f / (1.f + __expf(-v2)));
      o.w = f2bf(1.f / (1.f + __expf(-v3)));
      *(ushort4*)&fst[16 + m][16 * w + 4 * q] = o;
    }
  }
  __syncthreads();

  {
    f32x4 a00 = {0, 0, 0, 0}, a01 = {0, 0, 0, 0};
    f32x4 a10 = {0, 0, 0, 0}, a11 = {0, 0, 0, 0};
    bf16x8 f00 = *(const bf16x8*)&fst[m][q * 8];
    bf16x8 f10 = *(const bf16x8*)&fst[16 + m][q * 8];
    a00 = __builtin_amdgcn_mfma_f32_16x16x32_bf16(f00, wb00, a00, 0, 0, 0);
    a10 = __builtin_amdgcn_mfma_f32_16x16x32_bf16(f00, wb10, a10, 0, 0, 0);
    a01 = __builtin_amdgcn_mfma_f32_16x16x32_bf16(f10, wb00, a01, 0, 0, 0);
    a11 = __builtin_amdgcn_mfma_f32_16x16x32_bf16(f10, wb10, a11, 0, 0, 0);
    bf16x8 f01 = *(const bf16x8*)&fst[m][q * 8 + 32];
    bf16x8 f11 = *(const bf16x8*)&fst[16 + m][q * 8 + 32];
    a00 = __builtin_amdgcn_mfma_f32_16x16x32_bf16(f01, wb01, a00, 0, 0, 0);
    a10 = __builtin_amdgcn_mfma_f32_16x16x32_bf16(f01, wb11, a10, 0, 0, 0);
    a01 = __builtin_amdgcn_mfma_f32_16x16x32_bf16(f11, wb01, a01, 0, 0, 0);
    a11 = __builtin_amdgcn_mfma_f32_16x16x32_bf16(f11, wb11, a11, 0, 0, 0);

#pragma unroll
    for (int mt = 0; mt < 2; ++mt)
#pragma unroll
      for (int nt = 0; nt < 2; ++nt) {
        f32x4 acc = mt == 0 ? (nt == 0 ? a00 : a01) : (nt == 0 ? a10 : a11);
#pragma unroll
        for (int r = 0; r < 4; ++r) {
          int row = 16 * nt + 4 * q + r;
          int n = n0 + (row >> 2), b = row & 3;
          float v = acc[r];
          __builtin_nontemporal_store(
              v > 0.f ? v : 0.f,
              out + ((size_t)b * NODES + n) * 128 + 32 * w + 16 * mt + m);
        }
      }
  }
}

extern "C" void kernel_launch(void* const* d_in, const int* in_sizes, int n_in,
                              void* d_out, int out_size, void* d_ws, size_t ws_size,
                              hipStream_t stream) {
  const float* x     = (const float*)d_in[0];
  const int*   ei    = (const int*)d_in[1];
  const float* lin_w = (const float*)d_in[2];
  const float* bias  = (const float*)d_in[3];
  const float* up1   = (const float*)d_in[4];
  const float* up2   = (const float*)d_in[5];
  const float* lo1   = (const float*)d_in[6];
  const float* lo2   = (const float*)d_in[7];
  const float* lastw = (const float*)d_in[8];
  float* out = (float*)d_out;

  char* ws = (char*)d_ws;
  unsigned short* wb16 = (unsigned short*)(ws);            // 24576 B
  float* dis        = (float*)(ws + (64 << 10));           // 80 KB
  int*   cnt        = (int*)(ws + (192 << 10));            // 80 KB
  int*   csr        = (int*)(ws + (1 << 20));              // NODES*CAP*4 = 5.12 MB
  unsigned int* xs8 = (unsigned int*)(ws + (8 << 20));     // NODES*256 B = 5.12 MB

  // MEASUREMENT: (memset+build) x4 — idempotent (cnt re-zeroed each time; csr
  // source-sets identical, only slot order varies -> fp reorder noise << tol).
  // dur_us - 147.5 = 3*(memset + build + gaps).
  for (int rep = 0; rep < 4; ++rep) {
    (void)hipMemsetAsync(cnt, 0, NODES * sizeof(int), stream);
    k_build<<<NEB + LINB + BIGB, 256, 0, stream>>>(ei, cnt, csr, lin_w, up1, up2,
                                                   lo1, lo2, lastw, wb16);
  }
  k_xconv<<<NODES / 4, 256, 0, stream>>>(cnt, dis, x, xs8);
  k_gpost<<<NODES / 8, 256, 0, stream>>>(cnt, csr, xs8, dis, bias, wb16, out);
}

// Round 6
// 139.112 us; speedup vs baseline: 2.3834x; 1.5053x over previous
//
#include <hip/hip_runtime.h>
#include <cstdint>
#include <cstddef>

#define NODES 20000
#define NEDGE 320000
#define CAP 64            // padded CSR capacity per node (max deg ~34)
#define SCATB 625         // NEDGE/(256*2) -- 2 edges per thread
#define LINB 16           // 4096/256
#define BIGB 32           // 8192/256
#define XCVB 5000         // NODES*64/256 xconv blocks
#define BLDB (SCATB + LINB + BIGB + XCVB)

using bf16x8 = __attribute__((ext_vector_type(8))) __bf16;
using f32x4  = __attribute__((ext_vector_type(4))) float;
using f32x2  = __attribute__((ext_vector_type(2))) float;
using us8    = __attribute__((ext_vector_type(8))) unsigned short;
using us4    = __attribute__((ext_vector_type(4))) unsigned short;

__device__ __forceinline__ unsigned short f2bf(float f) {
  union { float f; unsigned int u; } v; v.f = f;
  unsigned int r = v.u + 0x7FFF + ((v.u >> 16) & 1);  // RNE
  return (unsigned short)(r >> 16);
}

// decode packed-fp8 dword, FMA-accumulate with per-neighbor weight dr
#define DECFMA(u, dr, s0, s1, s2, s3)                           \
  {                                                             \
    f32x2 lo_ = __builtin_amdgcn_cvt_pk_f32_fp8(u, false);      \
    f32x2 hi_ = __builtin_amdgcn_cvt_pk_f32_fp8(u, true);       \
    s0 += dr * lo_.x; s1 += dr * lo_.y;                         \
    s2 += dr * hi_.x; s3 += dr * hi_.y;                         \
  }

// ---------------- build: CSR(u16) scatter + weights + xconv, one grid ----------------
// xs8 = fp8(x) UNSCALED (no cnt dependency -> xconv merged here, overlaps scatter).
// wb16 layout: [0,4096) lin ; [4096,12288) BigW[128][64]
__global__ void k_build(const int* __restrict__ ei, int* __restrict__ cnt,
                        unsigned short* __restrict__ csr16,
                        const float* __restrict__ lin, const float* __restrict__ u1,
                        const float* __restrict__ u2, const float* __restrict__ l1,
                        const float* __restrict__ l2, const float* __restrict__ lastw,
                        unsigned short* __restrict__ wb16,
                        const float* __restrict__ x, unsigned int* __restrict__ xs8) {
  __shared__ float tmp_u[4][64];
  __shared__ float tmp_l[4][64];
  int bid = blockIdx.x, t = threadIdx.x;
  if (bid < SCATB) {
    int i = (bid * 256 + t) * 2;          // 625*256*2 == NEDGE exactly
    int2 r2 = *(const int2*)(ei + i);
    int2 c2 = *(const int2*)(ei + NEDGE + i);
    int p0 = atomicAdd(&cnt[c2.x], 1);
    if (p0 < CAP) csr16[c2.x * CAP + p0] = (unsigned short)r2.x;
    int p1 = atomicAdd(&cnt[c2.y], 1);
    if (p1 < CAP) csr16[c2.y * CAP + p1] = (unsigned short)r2.y;
  } else if (bid < SCATB + LINB) {
    int g = (bid - SCATB) * 256 + t;  // [0,4096)
    wb16[g] = f2bf(lin[g]);
  } else if (bid < SCATB + LINB + BIGB) {
    // BigW[o][j] = sum_p (sum_k last[o][k] u2[k][p]) u1[p][j]
    //            + sum_p (sum_k last[o][64+k] l2[k][p]) l1[p][j]
    int o0 = (bid - SCATB - LINB) * 4;
    int ol = t >> 6, p = t & 63;
    float su = 0.f, sl = 0.f;
    for (int k = 0; k < 64; ++k) {
      float lu = lastw[(o0 + ol) * 128 + k];
      float ll = lastw[(o0 + ol) * 128 + 64 + k];
      su += lu * u2[k * 64 + p];
      sl += ll * l2[k * 64 + p];
    }
    tmp_u[ol][p] = su;
    tmp_l[ol][p] = sl;
    __syncthreads();
    float acc = 0.f;
    for (int q = 0; q < 64; ++q)
      acc += tmp_u[ol][q] * u1[q * 64 + p] + tmp_l[ol][q] * l1[q * 64 + p];
    wb16[4096 + (o0 + ol) * 64 + p] = f2bf(acc);
  } else {
    int g = (bid - SCATB - LINB - BIGB) * 256 + t;  // [0, NODES*64)
    int n = g >> 6, i = g & 63;
    int b = i >> 4, c = (i & 15) * 4;
    f32x4 v = __builtin_nontemporal_load(
        (const f32x4*)(x + ((size_t)b * NODES + n) * 64 + c));
    int p = 0;
    p = __builtin_amdgcn_cvt_pk_fp8_f32(v.x, v.y, p, false);  // bytes 0,1
    p = __builtin_amdgcn_cvt_pk_fp8_f32(v.z, v.w, p, true);   // bytes 2,3
    xs8[(size_t)n * 64 + i] = (unsigned int)p;
  }
}

// ---------------- fused gather(fp8,dis-weighted) + lin + sigmoid + BigW + relu ------
// block = 8 nodes, 8 waves (512 thr); each wave gathers ONE node (halved chain).
// dis computed inline as rsqrt(cnt+1); neighbor weight dis[row] applied as f32 FMA.
// stage1 (swapped, waves 0-3): h^T[feat][row]; fst = sigmoid(h*dis[col]+bias) -> LDS
// stage2 (natural, 8 waves x 16 cols): D[row][oc] = fst @ BigW^T -> relu -> stores
__global__ __launch_bounds__(512) void k_gpost(const int* __restrict__ cnt,
                                               const unsigned short* __restrict__ csr16,
                                               const unsigned int* __restrict__ xs8,
                                               const float* __restrict__ bias,
                                               const unsigned short* __restrict__ wb16,
                                               float* __restrict__ out) {
  __shared__ unsigned short xa[32][72];
  __shared__ unsigned short fst[32][72];
  int t = threadIdx.x;
  int w = t >> 6, l = t & 63;
  int n0 = blockIdx.x * 8;
  int n = n0 + w;  // this wave's node

  int cn = cnt[n];
  int dn = cn > CAP ? CAP : cn;
  float dsn = rsqrtf((float)(cn + 1));  // +1 = self loop

  float a0, a1, a2, a3;
  {
    unsigned int u = xs8[(size_t)n * 64 + l];  // self loop, weight dis[n]
    f32x2 lo = __builtin_amdgcn_cvt_pk_f32_fp8(u, false);
    f32x2 hi = __builtin_amdgcn_cvt_pk_f32_fp8(u, true);
    a0 = dsn * lo.x; a1 = dsn * lo.y; a2 = dsn * hi.x; a3 = dsn * hi.y;
  }

  int base = n * CAP, i = 0;
  for (; i + 8 <= dn; i += 8) {  // 8-deep: 8 idx + 8 cnt + 8 xs8 loads in flight
    us8 r8 = __builtin_nontemporal_load((const us8*)(csr16 + base + i));
    int r0 = r8[0], r1 = r8[1], r2 = r8[2], r3 = r8[3];
    int r4 = r8[4], r5 = r8[5], r6 = r8[6], r7 = r8[7];
    int c0 = cnt[r0], c1 = cnt[r1], c2 = cnt[r2], c3 = cnt[r3];
    int c4 = cnt[r4], c5 = cnt[r5], c6 = cnt[r6], c7 = cnt[r7];
    unsigned int u0 = xs8[(size_t)r0 * 64 + l];
    unsigned int u1 = xs8[(size_t)r1 * 64 + l];
    unsigned int u2 = xs8[(size_t)r2 * 64 + l];
    unsigned int u3 = xs8[(size_t)r3 * 64 + l];
    unsigned int u4 = xs8[(size_t)r4 * 64 + l];
    unsigned int u5 = xs8[(size_t)r5 * 64 + l];
    unsigned int u6 = xs8[(size_t)r6 * 64 + l];
    unsigned int u7 = xs8[(size_t)r7 * 64 + l];
    float d0 = rsqrtf((float)(c0 + 1)), d1 = rsqrtf((float)(c1 + 1));
    float d2 = rsqrtf((float)(c2 + 1)), d3 = rsqrtf((float)(c3 + 1));
    float d4 = rsqrtf((float)(c4 + 1)), d5 = rsqrtf((float)(c5 + 1));
    float d6 = rsqrtf((float)(c6 + 1)), d7 = rsqrtf((float)(c7 + 1));
    DECFMA(u0, d0, a0, a1, a2, a3); DECFMA(u1, d1, a0, a1, a2, a3);
    DECFMA(u2, d2, a0, a1, a2, a3); DECFMA(u3, d3, a0, a1, a2, a3);
    DECFMA(u4, d4, a0, a1, a2, a3); DECFMA(u5, d5, a0, a1, a2, a3);
    DECFMA(u6, d6, a0, a1, a2, a3); DECFMA(u7, d7, a0, a1, a2, a3);
  }
  if (i + 4 <= dn) {
    us4 r4v = __builtin_nontemporal_load((const us4*)(csr16 + base + i));
    int r0 = r4v[0], r1 = r4v[1], r2 = r4v[2], r3 = r4v[3];
    int c0 = cnt[r0], c1 = cnt[r1], c2 = cnt[r2], c3 = cnt[r3];
    unsigned int u0 = xs8[(size_t)r0 * 64 + l];
    unsigned int u1 = xs8[(size_t)r1 * 64 + l];
    unsigned int u2 = xs8[(size_t)r2 * 64 + l];
    unsigned int u3 = xs8[(size_t)r3 * 64 + l];
    float d0 = rsqrtf((float)(c0 + 1)), d1 = rsqrtf((float)(c1 + 1));
    float d2 = rsqrtf((float)(c2 + 1)), d3 = rsqrtf((float)(c3 + 1));
    DECFMA(u0, d0, a0, a1, a2, a3); DECFMA(u1, d1, a0, a1, a2, a3);
    DECFMA(u2, d2, a0, a1, a2, a3); DECFMA(u3, d3, a0, a1, a2, a3);
    i += 4;
  }
  for (; i < dn; ++i) {
    int r = csr16[base + i];
    float dr = rsqrtf((float)(cnt[r] + 1));
    unsigned int u = xs8[(size_t)r * 64 + l];
    DECFMA(u, dr, a0, a1, a2, a3);
  }

  {
    ushort4 o;
    o.x = f2bf(a0); o.y = f2bf(a1); o.z = f2bf(a2); o.w = f2bf(a3);
    // row = node_local*4 + batch; node_local = w, batch = l>>4
    *(ushort4*)&xa[w * 4 + (l >> 4)][(l & 15) * 4] = o;
  }

  int m = l & 15, q = l >> 4;
  const unsigned short* wlin = wb16;
  const unsigned short* bigw = wb16 + 4096;
  int ws1 = w & 3;  // stage1 wave role (waves 4-7 idle in stage1)

  // prefetch weights/bias/dis before the barrier -> latency hides
  bf16x8 wa0 = *(const bf16x8*)(wlin + (16 * ws1 + m) * 64 + q * 8);
  bf16x8 wa1 = *(const bf16x8*)(wlin + (16 * ws1 + m) * 64 + q * 8 + 32);
  bf16x8 wbk0 = *(const bf16x8*)(bigw + (16 * w + m) * 64 + q * 8);       // kk=0
  bf16x8 wbk1 = *(const bf16x8*)(bigw + (16 * w + m) * 64 + q * 8 + 32);  // kk=1
  float4 b4 = *(const float4*)(bias + 16 * ws1 + 4 * q);
  float ds0 = rsqrtf((float)(cnt[n0 + (m >> 2)] + 1));      // nt=0: row=m
  float ds1 = rsqrtf((float)(cnt[n0 + 4 + (m >> 2)] + 1));  // nt=1: row=16+m

  __syncthreads();

  // stage1 (swapped): D[feat=16*ws1+4q+reg][row=16nt+m]; only waves 0-3
  if (w < 4) {
    f32x4 acc10 = {0, 0, 0, 0}, acc11 = {0, 0, 0, 0};
    bf16x8 x00 = *(const bf16x8*)&xa[m][q * 8];
    bf16x8 x10 = *(const bf16x8*)&xa[16 + m][q * 8];
    acc10 = __builtin_amdgcn_mfma_f32_16x16x32_bf16(wa0, x00, acc10, 0, 0, 0);
    acc11 = __builtin_amdgcn_mfma_f32_16x16x32_bf16(wa0, x10, acc11, 0, 0, 0);
    bf16x8 x01 = *(const bf16x8*)&xa[m][q * 8 + 32];
    bf16x8 x11 = *(const bf16x8*)&xa[16 + m][q * 8 + 32];
    acc10 = __builtin_amdgcn_mfma_f32_16x16x32_bf16(wa1, x01, acc10, 0, 0, 0);
    acc11 = __builtin_amdgcn_mfma_f32_16x16x32_bf16(wa1, x11, acc11, 0, 0, 0);
    {
      float v0 = acc10[0] * ds0 + b4.x;
      float v1 = acc10[1] * ds0 + b4.y;
      float v2 = acc10[2] * ds0 + b4.z;
      float v3 = acc10[3] * ds0 + b4.w;
      ushort4 o;
      o.x = f2bf(1.f / (1.f + __expf(-v0)));
      o.y = f2bf(1.f / (1.f + __expf(-v1)));
      o.z = f2bf(1.f / (1.f + __expf(-v2)));
      o.w = f2bf(1.f / (1.f + __expf(-v3)));
      *(ushort4*)&fst[m][16 * ws1 + 4 * q] = o;
    }
    {
      float v0 = acc11[0] * ds1 + b4.x;
      float v1 = acc11[1] * ds1 + b4.y;
      float v2 = acc11[2] * ds1 + b4.z;
      float v3 = acc11[3] * ds1 + b4.w;
      ushort4 o;
      o.x = f2bf(1.f / (1.f + __expf(-v0)));
      o.y = f2bf(1.f / (1.f + __expf(-v1)));
      o.z = f2bf(1.f / (1.f + __expf(-v2)));
      o.w = f2bf(1.f / (1.f + __expf(-v3)));
      *(ushort4*)&fst[16 + m][16 * ws1 + 4 * q] = o;
    }
  }
  __syncthreads();

  // stage2 (natural): wave w covers cols 16w..16w+15; D[row=16nt+4q+reg][col]
  {
    f32x4 a00 = {0, 0, 0, 0}, a01 = {0, 0, 0, 0};  // a<nt>
    bf16x8 f00 = *(const bf16x8*)&fst[m][q * 8];          // nt=0, kk=0
    bf16x8 f10 = *(const bf16x8*)&fst[16 + m][q * 8];     // nt=1, kk=0
    a00 = __builtin_amdgcn_mfma_f32_16x16x32_bf16(f00, wbk0, a00, 0, 0, 0);
    a01 = __builtin_amdgcn_mfma_f32_16x16x32_bf16(f10, wbk0, a01, 0, 0, 0);
    bf16x8 f01 = *(const bf16x8*)&fst[m][q * 8 + 32];     // nt=0, kk=1
    bf16x8 f11 = *(const bf16x8*)&fst[16 + m][q * 8 + 32];// nt=1, kk=1
    a00 = __builtin_amdgcn_mfma_f32_16x16x32_bf16(f01, wbk1, a00, 0, 0, 0);
    a01 = __builtin_amdgcn_mfma_f32_16x16x32_bf16(f11, wbk1, a01, 0, 0, 0);

#pragma unroll
    for (int nt = 0; nt < 2; ++nt) {
      f32x4 acc = nt == 0 ? a00 : a01;
#pragma unroll
      for (int r = 0; r < 4; ++r) {
        int row = 16 * nt + 4 * q + r;  // lanes m=0..15 share this row
        int nn = n0 + (row >> 2), b = row & 3;
        float v = acc[r];
        __builtin_nontemporal_store(
            v > 0.f ? v : 0.f,
            out + ((size_t)b * NODES + nn) * 128 + 16 * w + m);
      }
    }
  }
}

extern "C" void kernel_launch(void* const* d_in, const int* in_sizes, int n_in,
                              void* d_out, int out_size, void* d_ws, size_t ws_size,
                              hipStream_t stream) {
  const float* x     = (const float*)d_in[0];
  const int*   ei    = (const int*)d_in[1];
  const float* lin_w = (const float*)d_in[2];
  const float* bias  = (const float*)d_in[3];
  const float* up1   = (const float*)d_in[4];
  const float* up2   = (const float*)d_in[5];
  const float* lo1   = (const float*)d_in[6];
  const float* lo2   = (const float*)d_in[7];
  const float* lastw = (const float*)d_in[8];
  float* out = (float*)d_out;

  char* ws = (char*)d_ws;
  unsigned short* wb16  = (unsigned short*)(ws);          // 24576 B
  int*            cnt   = (int*)(ws + (192 << 10));       // 80 KB
  unsigned short* csr16 = (unsigned short*)(ws + (1 << 20));  // NODES*CAP*2 = 2.56 MB
  unsigned int*   xs8   = (unsigned int*)(ws + (8 << 20));    // NODES*256 B = 5.12 MB

  (void)hipMemsetAsync(cnt, 0, NODES * sizeof(int), stream);
  k_build<<<BLDB, 256, 0, stream>>>(ei, cnt, csr16, lin_w, up1, up2, lo1, lo2,
                                    lastw, wb16, x, xs8);
  k_gpost<<<NODES / 8, 512, 0, stream>>>(cnt, csr16, xs8, bias, wb16, out);
}

// Round 7
// 135.154 us; speedup vs baseline: 2.4531x; 1.0293x over previous
//
#include <hip/hip_runtime.h>
#include <cstdint>
#include <cstddef>

#define NODES 20000
#define NEDGE 320000
#define CAP 64            // padded CSR capacity per node (max deg ~34)
#define SCATB 625         // NEDGE/(256*2) -- 2 edges per thread
#define LINB 16           // 4096/256
#define BIGB 32           // 8192/256
#define XCVB 5000         // NODES*64/256 xconv blocks
#define BLDB (SCATB + LINB + BIGB + XCVB)

using bf16x8 = __attribute__((ext_vector_type(8))) __bf16;
using f32x4  = __attribute__((ext_vector_type(4))) float;
using f32x2  = __attribute__((ext_vector_type(2))) float;
using us8    = __attribute__((ext_vector_type(8))) unsigned short;

__device__ __forceinline__ unsigned short f2bf(float f) {
  union { float f; unsigned int u; } v; v.f = f;
  unsigned int r = v.u + 0x7FFF + ((v.u >> 16) & 1);  // RNE
  return (unsigned short)(r >> 16);
}

// decode packed-fp8 dword, FMA-accumulate with per-neighbor weight dr
#define DECFMA(u, dr, s0, s1, s2, s3)                           \
  {                                                             \
    f32x2 lo_ = __builtin_amdgcn_cvt_pk_f32_fp8(u, false);      \
    f32x2 hi_ = __builtin_amdgcn_cvt_pk_f32_fp8(u, true);       \
    s0 += dr * lo_.x; s1 += dr * lo_.y;                         \
    s2 += dr * hi_.x; s3 += dr * hi_.y;                         \
  }

// ---------------- build: CSR(u16) scatter + weights + xconv, one grid ----------------
// xs8 = fp8(x) UNSCALED (no cnt dependency -> xconv merged here, overlaps scatter).
// wb16 layout: [0,4096) lin ; [4096,12288) BigW[128][64]
__global__ void k_build(const int* __restrict__ ei, int* __restrict__ cnt,
                        unsigned short* __restrict__ csr16,
                        const float* __restrict__ lin, const float* __restrict__ u1,
                        const float* __restrict__ u2, const float* __restrict__ l1,
                        const float* __restrict__ l2, const float* __restrict__ lastw,
                        unsigned short* __restrict__ wb16,
                        const float* __restrict__ x, unsigned int* __restrict__ xs8) {
  __shared__ float tmp_u[4][64];
  __shared__ float tmp_l[4][64];
  int bid = blockIdx.x, t = threadIdx.x;
  if (bid < SCATB) {
    int i = (bid * 256 + t) * 2;          // 625*256*2 == NEDGE exactly
    int2 r2 = *(const int2*)(ei + i);
    int2 c2 = *(const int2*)(ei + NEDGE + i);
    int p0 = atomicAdd(&cnt[c2.x], 1);
    if (p0 < CAP) csr16[c2.x * CAP + p0] = (unsigned short)r2.x;
    int p1 = atomicAdd(&cnt[c2.y], 1);
    if (p1 < CAP) csr16[c2.y * CAP + p1] = (unsigned short)r2.y;
  } else if (bid < SCATB + LINB) {
    int g = (bid - SCATB) * 256 + t;  // [0,4096)
    wb16[g] = f2bf(lin[g]);
  } else if (bid < SCATB + LINB + BIGB) {
    // BigW[o][j] = sum_p (sum_k last[o][k] u2[k][p]) u1[p][j]
    //            + sum_p (sum_k last[o][64+k] l2[k][p]) l1[p][j]
    int o0 = (bid - SCATB - LINB) * 4;
    int ol = t >> 6, p = t & 63;
    float su = 0.f, sl = 0.f;
    for (int k = 0; k < 64; ++k) {
      float lu = lastw[(o0 + ol) * 128 + k];
      float ll = lastw[(o0 + ol) * 128 + 64 + k];
      su += lu * u2[k * 64 + p];
      sl += ll * l2[k * 64 + p];
    }
    tmp_u[ol][p] = su;
    tmp_l[ol][p] = sl;
    __syncthreads();
    float acc = 0.f;
    for (int q = 0; q < 64; ++q)
      acc += tmp_u[ol][q] * u1[q * 64 + p] + tmp_l[ol][q] * l1[q * 64 + p];
    wb16[4096 + (o0 + ol) * 64 + p] = f2bf(acc);
  } else {
    int g = (bid - SCATB - LINB - BIGB) * 256 + t;  // [0, NODES*64)
    int n = g >> 6, i = g & 63;
    int b = i >> 4, c = (i & 15) * 4;
    f32x4 v = __builtin_nontemporal_load(
        (const f32x4*)(x + ((size_t)b * NODES + n) * 64 + c));
    int p = 0;
    p = __builtin_amdgcn_cvt_pk_fp8_f32(v.x, v.y, p, false);  // bytes 0,1
    p = __builtin_amdgcn_cvt_pk_fp8_f32(v.z, v.w, p, true);   // bytes 2,3
    xs8[(size_t)n * 64 + i] = (unsigned int)p;
  }
}

// ---------------- fused gather(fp8,dis-weighted) + lin + sigmoid + BigW + relu ------
// block = 8 nodes, 8 waves (512 thr); each wave gathers ONE node.
// Gather is FLAT: all CSR indices hoisted (3x us8 = 24, P(deg<=24)~98%), then a
// 16-wide fully-parallel masked batch (invalid j -> r=n, d=0) -> single
// idx->data dependence level. Remainder uses pre-hoisted rr2 (no new idx dep).
// stage1 (swapped, waves 0-3): h^T[feat][row]; fst = sigmoid(h*dis[col]+bias) -> LDS
// stage2 (natural, 8 waves x 16 cols): D[row][oc] = fst @ BigW^T -> relu -> stores
__global__ __launch_bounds__(512) void k_gpost(const int* __restrict__ cnt,
                                               const unsigned short* __restrict__ csr16,
                                               const unsigned int* __restrict__ xs8,
                                               const float* __restrict__ bias,
                                               const unsigned short* __restrict__ wb16,
                                               float* __restrict__ out) {
  __shared__ unsigned short xa[32][72];
  __shared__ unsigned short fst[32][72];
  int t = threadIdx.x;
  int w = t >> 6, l = t & 63;
  int n0 = blockIdx.x * 8;
  int n = n0 + w;  // this wave's node

  int cn = cnt[n];
  int dn = cn > CAP ? CAP : cn;
  float dsn = rsqrtf((float)(cn + 1));  // +1 = self loop
  int base = n * CAP;

  // hoist ALL index loads (no dependencies) + self-loop data load
  us8 rr0 = *(const us8*)(csr16 + base);
  us8 rr1 = *(const us8*)(csr16 + base + 8);
  us8 rr2 = *(const us8*)(csr16 + base + 16);
  unsigned int uself = xs8[(size_t)n * 64 + l];

  float a0, a1, a2, a3;
  {
    f32x2 lo = __builtin_amdgcn_cvt_pk_f32_fp8(uself, false);
    f32x2 hi = __builtin_amdgcn_cvt_pk_f32_fp8(uself, true);
    a0 = dsn * lo.x; a1 = dsn * lo.y; a2 = dsn * hi.x; a3 = dsn * hi.y;
  }

  // 16-wide parallel masked batch (covers deg<=16, ~57% of nodes fully)
  {
    int r[16]; int c[16]; unsigned int uu[16];
#pragma unroll
    for (int j = 0; j < 16; ++j) {
      int rj = (j < 8) ? (int)rr0[j] : (int)rr1[j - 8];
      r[j] = (j < dn) ? rj : n;  // masked -> self (valid addr, weight 0)
    }
#pragma unroll
    for (int j = 0; j < 16; ++j) c[j] = cnt[r[j]];
#pragma unroll
    for (int j = 0; j < 16; ++j) uu[j] = xs8[(size_t)r[j] * 64 + l];
#pragma unroll
    for (int j = 0; j < 16; ++j) {
      float dj = (j < dn) ? rsqrtf((float)(c[j] + 1)) : 0.f;
      DECFMA(uu[j], dj, a0, a1, a2, a3);
    }
  }
  if (dn > 16) {
    // batch 2 (j=16..23): idx already in rr2 -> chain is xs8-only
    {
      int r[8]; int c[8]; unsigned int uu[8];
#pragma unroll
      for (int j = 0; j < 8; ++j) {
        int rj = (int)rr2[j];
        r[j] = (16 + j < dn) ? rj : n;
      }
#pragma unroll
      for (int j = 0; j < 8; ++j) c[j] = cnt[r[j]];
#pragma unroll
      for (int j = 0; j < 8; ++j) uu[j] = xs8[(size_t)r[j] * 64 + l];
#pragma unroll
      for (int j = 0; j < 8; ++j) {
        float dj = (16 + j < dn) ? rsqrtf((float)(c[j] + 1)) : 0.f;
        DECFMA(uu[j], dj, a0, a1, a2, a3);
      }
    }
    // rare tail (deg > 24), masked batches of 8
    for (int i = 24; i < dn; i += 8) {
      us8 rv = *(const us8*)(csr16 + base + i);
      int r[8]; int c[8]; unsigned int uu[8];
#pragma unroll
      for (int j = 0; j < 8; ++j) {
        int rj = (int)rv[j];
        r[j] = (i + j < dn) ? rj : n;
      }
#pragma unroll
      for (int j = 0; j < 8; ++j) c[j] = cnt[r[j]];
#pragma unroll
      for (int j = 0; j < 8; ++j) uu[j] = xs8[(size_t)r[j] * 64 + l];
#pragma unroll
      for (int j = 0; j < 8; ++j) {
        float dj = (i + j < dn) ? rsqrtf((float)(c[j] + 1)) : 0.f;
        DECFMA(uu[j], dj, a0, a1, a2, a3);
      }
    }
  }

  {
    ushort4 o;
    o.x = f2bf(a0); o.y = f2bf(a1); o.z = f2bf(a2); o.w = f2bf(a3);
    // row = node_local*4 + batch; node_local = w, batch = l>>4
    *(ushort4*)&xa[w * 4 + (l >> 4)][(l & 15) * 4] = o;
  }

  int m = l & 15, q = l >> 4;
  const unsigned short* wlin = wb16;
  const unsigned short* bigw = wb16 + 4096;
  int ws1 = w & 3;  // stage1 wave role (waves 4-7 idle in stage1)

  // prefetch weights/bias/dis before the barrier -> latency hides
  bf16x8 wa0 = *(const bf16x8*)(wlin + (16 * ws1 + m) * 64 + q * 8);
  bf16x8 wa1 = *(const bf16x8*)(wlin + (16 * ws1 + m) * 64 + q * 8 + 32);
  bf16x8 wbk0 = *(const bf16x8*)(bigw + (16 * w + m) * 64 + q * 8);       // kk=0
  bf16x8 wbk1 = *(const bf16x8*)(bigw + (16 * w + m) * 64 + q * 8 + 32);  // kk=1
  float4 b4 = *(const float4*)(bias + 16 * ws1 + 4 * q);
  float ds0 = rsqrtf((float)(cnt[n0 + (m >> 2)] + 1));      // nt=0: row=m
  float ds1 = rsqrtf((float)(cnt[n0 + 4 + (m >> 2)] + 1));  // nt=1: row=16+m

  __syncthreads();

  // stage1 (swapped): D[feat=16*ws1+4q+reg][row=16nt+m]; only waves 0-3
  if (w < 4) {
    f32x4 acc10 = {0, 0, 0, 0}, acc11 = {0, 0, 0, 0};
    bf16x8 x00 = *(const bf16x8*)&xa[m][q * 8];
    bf16x8 x10 = *(const bf16x8*)&xa[16 + m][q * 8];
    acc10 = __builtin_amdgcn_mfma_f32_16x16x32_bf16(wa0, x00, acc10, 0, 0, 0);
    acc11 = __builtin_amdgcn_mfma_f32_16x16x32_bf16(wa0, x10, acc11, 0, 0, 0);
    bf16x8 x01 = *(const bf16x8*)&xa[m][q * 8 + 32];
    bf16x8 x11 = *(const bf16x8*)&xa[16 + m][q * 8 + 32];
    acc10 = __builtin_amdgcn_mfma_f32_16x16x32_bf16(wa1, x01, acc10, 0, 0, 0);
    acc11 = __builtin_amdgcn_mfma_f32_16x16x32_bf16(wa1, x11, acc11, 0, 0, 0);
    {
      float v0 = acc10[0] * ds0 + b4.x;
      float v1 = acc10[1] * ds0 + b4.y;
      float v2 = acc10[2] * ds0 + b4.z;
      float v3 = acc10[3] * ds0 + b4.w;
      ushort4 o;
      o.x = f2bf(1.f / (1.f + __expf(-v0)));
      o.y = f2bf(1.f / (1.f + __expf(-v1)));
      o.z = f2bf(1.f / (1.f + __expf(-v2)));
      o.w = f2bf(1.f / (1.f + __expf(-v3)));
      *(ushort4*)&fst[m][16 * ws1 + 4 * q] = o;
    }
    {
      float v0 = acc11[0] * ds1 + b4.x;
      float v1 = acc11[1] * ds1 + b4.y;
      float v2 = acc11[2] * ds1 + b4.z;
      float v3 = acc11[3] * ds1 + b4.w;
      ushort4 o;
      o.x = f2bf(1.f / (1.f + __expf(-v0)));
      o.y = f2bf(1.f / (1.f + __expf(-v1)));
      o.z = f2bf(1.f / (1.f + __expf(-v2)));
      o.w = f2bf(1.f / (1.f + __expf(-v3)));
      *(ushort4*)&fst[16 + m][16 * ws1 + 4 * q] = o;
    }
  }
  __syncthreads();

  // stage2 (natural): wave w covers cols 16w..16w+15; D[row=16nt+4q+reg][col]
  {
    f32x4 a00 = {0, 0, 0, 0}, a01 = {0, 0, 0, 0};  // a<nt>
    bf16x8 f00 = *(const bf16x8*)&fst[m][q * 8];          // nt=0, kk=0
    bf16x8 f10 = *(const bf16x8*)&fst[16 + m][q * 8];     // nt=1, kk=0
    a00 = __builtin_amdgcn_mfma_f32_16x16x32_bf16(f00, wbk0, a00, 0, 0, 0);
    a01 = __builtin_amdgcn_mfma_f32_16x16x32_bf16(f10, wbk0, a01, 0, 0, 0);
    bf16x8 f01 = *(const bf16x8*)&fst[m][q * 8 + 32];     // nt=0, kk=1
    bf16x8 f11 = *(const bf16x8*)&fst[16 + m][q * 8 + 32];// nt=1, kk=1
    a00 = __builtin_amdgcn_mfma_f32_16x16x32_bf16(f01, wbk1, a00, 0, 0, 0);
    a01 = __builtin_amdgcn_mfma_f32_16x16x32_bf16(f11, wbk1, a01, 0, 0, 0);

#pragma unroll
    for (int nt = 0; nt < 2; ++nt) {
      f32x4 acc = nt == 0 ? a00 : a01;
#pragma unroll
      for (int r = 0; r < 4; ++r) {
        int row = 16 * nt + 4 * q + r;  // lanes m=0..15 share this row
        int nn = n0 + (row >> 2), b = row & 3;
        float v = acc[r];
        __builtin_nontemporal_store(
            v > 0.f ? v : 0.f,
            out + ((size_t)b * NODES + nn) * 128 + 16 * w + m);
      }
    }
  }
}

extern "C" void kernel_launch(void* const* d_in, const int* in_sizes, int n_in,
                              void* d_out, int out_size, void* d_ws, size_t ws_size,
                              hipStream_t stream) {
  const float* x     = (const float*)d_in[0];
  const int*   ei    = (const int*)d_in[1];
  const float* lin_w = (const float*)d_in[2];
  const float* bias  = (const float*)d_in[3];
  const float* up1   = (const float*)d_in[4];
  const float* up2   = (const float*)d_in[5];
  const float* lo1   = (const float*)d_in[6];
  const float* lo2   = (const float*)d_in[7];
  const float* lastw = (const float*)d_in[8];
  float* out = (float*)d_out;

  char* ws = (char*)d_ws;
  unsigned short* wb16  = (unsigned short*)(ws);          // 24576 B
  int*            cnt   = (int*)(ws + (192 << 10));       // 80 KB
  unsigned short* csr16 = (unsigned short*)(ws + (1 << 20));  // NODES*CAP*2 = 2.56 MB
  unsigned int*   xs8   = (unsigned int*)(ws + (8 << 20));    // NODES*256 B = 5.12 MB

  (void)hipMemsetAsync(cnt, 0, NODES * sizeof(int), stream);
  k_build<<<BLDB, 256, 0, stream>>>(ei, cnt, csr16, lin_w, up1, up2, lo1, lo2,
                                    lastw, wb16, x, xs8);
  k_gpost<<<NODES / 8, 512, 0, stream>>>(cnt, csr16, xs8, bias, wb16, out);
}